// Round 1
// baseline (372.408 us; speedup 1.0000x reference)
//
#include <hip/hip_runtime.h>

#define TEMPERATURE 0.07f
#define EPS 1e-8f
#define IGNORE_LABEL (-1)

// ---------------------------------------------------------------------------
// Pass 1 (edges): for each edge e with source i, dest j:
//   valid = label[i] != -1 && label[j] != -1
//   if valid:  w = exp(logit/T);  total[i] += w;
//              if label[i]==label[j]: pos[i] += w;  else flag[i] = 1
// Key factorization: denominator[i] = flag[i] ? total[i] : 0, same for
// numerator — so no second edge pass is needed.
// ---------------------------------------------------------------------------
__global__ void cbl_edge_kernel(const int* __restrict__ idx_i,
                                const int* __restrict__ idx_j,
                                const float* __restrict__ logits,
                                const int* __restrict__ label,
                                float* __restrict__ total,
                                float* __restrict__ pos,
                                int* __restrict__ flag,
                                int E) {
    int stride = gridDim.x * blockDim.x;
    for (int e = blockIdx.x * blockDim.x + threadIdx.x; e < E; e += stride) {
        int i  = idx_i[e];
        int j  = idx_j[e];
        int li = label[i];
        int lj = label[j];
        if (li == IGNORE_LABEL || lj == IGNORE_LABEL) continue;
        float w = __expf(logits[e] * (1.0f / TEMPERATURE));
        atomicAdd(&total[i], w);
        if (li == lj) {
            atomicAdd(&pos[i], w);
        } else {
            flag[i] = 1;   // benign race: all writers store 1
        }
    }
}

// ---------------------------------------------------------------------------
// Pass 2 (nodes): per_node = (flag && total>0) ? log(total+eps)-log(pos+eps) : 0
// Block-reduced into acc[0]=sum, acc[1]=count.
// ---------------------------------------------------------------------------
__global__ void cbl_node_kernel(const float* __restrict__ total,
                                const float* __restrict__ pos,
                                const int* __restrict__ flag,
                                float* __restrict__ acc,
                                int N) {
    float local_sum = 0.0f;
    float local_cnt = 0.0f;
    int stride = gridDim.x * blockDim.x;
    for (int i = blockIdx.x * blockDim.x + threadIdx.x; i < N; i += stride) {
        if (flag[i]) {
            float den = total[i];
            if (den > 0.0f) {
                local_sum += logf(den + EPS) - logf(pos[i] + EPS);
                local_cnt += 1.0f;
            }
        }
    }
    // wave(64)-level reduction
    for (int off = 32; off > 0; off >>= 1) {
        local_sum += __shfl_down(local_sum, off, 64);
        local_cnt += __shfl_down(local_cnt, off, 64);
    }
    __shared__ float s_sum[8];
    __shared__ float s_cnt[8];
    int wid  = threadIdx.x >> 6;
    int lane = threadIdx.x & 63;
    if (lane == 0) { s_sum[wid] = local_sum; s_cnt[wid] = local_cnt; }
    __syncthreads();
    if (threadIdx.x == 0) {
        float bs = 0.0f, bc = 0.0f;
        int nw = blockDim.x >> 6;
        for (int w = 0; w < nw; ++w) { bs += s_sum[w]; bc += s_cnt[w]; }
        atomicAdd(&acc[0], bs);
        atomicAdd(&acc[1], bc);
    }
}

__global__ void cbl_finalize_kernel(const float* __restrict__ acc,
                                    float* __restrict__ out) {
    out[0] = acc[0] / fmaxf(acc[1], 1.0f);
}

extern "C" void kernel_launch(void* const* d_in, const int* in_sizes, int n_in,
                              void* d_out, int out_size, void* d_ws, size_t ws_size,
                              hipStream_t stream) {
    const int*   edge_index = (const int*)d_in[0];    // (2, E) flat: [idx_i | idx_j]
    const float* logits     = (const float*)d_in[1];  // (E,)
    const int*   label      = (const int*)d_in[2];    // (N,)

    const int E = in_sizes[1];
    const int N = in_sizes[2];

    const int* idx_i = edge_index;
    const int* idx_j = edge_index + E;

    // workspace layout: total[N] f32 | pos[N] f32 | flag[N] i32 | acc[2] f32
    float* total = (float*)d_ws;
    float* pos   = total + N;
    int*   flag  = (int*)(pos + N);
    float* acc   = (float*)(flag + N);

    size_t ws_need = (size_t)N * 12 + 2 * sizeof(float);
    hipMemsetAsync(d_ws, 0, ws_need, stream);

    const int block = 256;
    int grid_e = (E + block - 1) / block;
    if (grid_e > 4096) grid_e = 4096;           // grid-stride the rest
    cbl_edge_kernel<<<grid_e, block, 0, stream>>>(idx_i, idx_j, logits, label,
                                                  total, pos, flag, E);

    int grid_n = (N + block - 1) / block;
    if (grid_n > 1024) grid_n = 1024;
    cbl_node_kernel<<<grid_n, block, 0, stream>>>(total, pos, flag, acc, N);

    cbl_finalize_kernel<<<1, 1, 0, stream>>>(acc, d_out ? (float*)d_out : nullptr);
}

// Round 2
// 356.263 us; speedup vs baseline: 1.0453x; 1.0453x over previous
//
#include <hip/hip_runtime.h>

#define INV_T   (1.0f / 0.07f)
#define EPS     1e-8f

// ---------------------------------------------------------------------------
// Label compression: int32 label -> u16 (IGNORE -1 -> 0xFFFF). 200KB array,
// L2-resident in every XCD, so the per-edge random gathers are L2 hits.
// ---------------------------------------------------------------------------
__global__ void cbl_pack_labels(const int* __restrict__ label,
                                unsigned short* __restrict__ lab16,
                                int N) {
    int i = blockIdx.x * blockDim.x + threadIdx.x;
    if (i < N) {
        int v = label[i];
        lab16[i] = (v == -1) ? 0xFFFFu : (unsigned short)v;
    }
}

// ---------------------------------------------------------------------------
// Edge pass, 4 edges per thread (int4/float4 loads, 8 independent gathers,
// up to 4 independent fire-and-forget atomics). Exactly ONE atomic per valid
// edge:
//   label_i == label_j  ->  possum[i] += w
//   else                ->  negsum[i] += w
// total = negsum + possum;  is_boundary <=> negsum > 0 (w > 0 always), so no
// flag array and no separate "total" accumulator are needed.
// ---------------------------------------------------------------------------
__device__ __forceinline__ void cbl_process_edge(int i, unsigned short li,
                                                 unsigned short lj, float w,
                                                 float* __restrict__ negsum,
                                                 float* __restrict__ possum) {
    if (li == 0xFFFFu || lj == 0xFFFFu) return;
    float* dst = (li == lj) ? possum : negsum;
    atomicAdd(dst + i, w);
}

__global__ __launch_bounds__(256) void cbl_edge_kernel_v4(
    const int* __restrict__ idx_i,
    const int* __restrict__ idx_j,
    const float* __restrict__ logits,
    const unsigned short* __restrict__ lab16,
    float* __restrict__ negsum,
    float* __restrict__ possum,
    int E) {
    int g = blockIdx.x * blockDim.x + threadIdx.x;
    int base = g * 4;
    if (base >= E) return;

    int4   ii = *reinterpret_cast<const int4*>(idx_i + base);
    int4   jj = *reinterpret_cast<const int4*>(idx_j + base);
    float4 lg = *reinterpret_cast<const float4*>(logits + base);

    // independent gathers (compiler can issue all 8 before waiting)
    unsigned short li0 = lab16[ii.x], li1 = lab16[ii.y];
    unsigned short li2 = lab16[ii.z], li3 = lab16[ii.w];
    unsigned short lj0 = lab16[jj.x], lj1 = lab16[jj.y];
    unsigned short lj2 = lab16[jj.z], lj3 = lab16[jj.w];

    float w0 = __expf(lg.x * INV_T);
    float w1 = __expf(lg.y * INV_T);
    float w2 = __expf(lg.z * INV_T);
    float w3 = __expf(lg.w * INV_T);

    cbl_process_edge(ii.x, li0, lj0, w0, negsum, possum);
    cbl_process_edge(ii.y, li1, lj1, w1, negsum, possum);
    cbl_process_edge(ii.z, li2, lj2, w2, negsum, possum);
    cbl_process_edge(ii.w, li3, lj3, w3, negsum, possum);
}

// scalar fallback (used only if E % 4 != 0)
__global__ __launch_bounds__(256) void cbl_edge_kernel_scalar(
    const int* __restrict__ idx_i,
    const int* __restrict__ idx_j,
    const float* __restrict__ logits,
    const unsigned short* __restrict__ lab16,
    float* __restrict__ negsum,
    float* __restrict__ possum,
    int E) {
    int stride = gridDim.x * blockDim.x;
    for (int e = blockIdx.x * blockDim.x + threadIdx.x; e < E; e += stride) {
        unsigned short li = lab16[idx_i[e]];
        unsigned short lj = lab16[idx_j[e]];
        float w = __expf(logits[e] * INV_T);
        cbl_process_edge(idx_i[e], li, lj, w, negsum, possum);
    }
}

// ---------------------------------------------------------------------------
// Node pass: boundary <=> negsum > 0; den = negsum + possum (> 0 automatic).
// ---------------------------------------------------------------------------
__global__ __launch_bounds__(256) void cbl_node_kernel(
    const float* __restrict__ negsum,
    const float* __restrict__ possum,
    float* __restrict__ acc,
    int N) {
    float local_sum = 0.0f;
    float local_cnt = 0.0f;
    int stride = gridDim.x * blockDim.x;
    for (int i = blockIdx.x * blockDim.x + threadIdx.x; i < N; i += stride) {
        float neg = negsum[i];
        if (neg > 0.0f) {
            float p   = possum[i];
            float den = neg + p;
            local_sum += logf(den + EPS) - logf(p + EPS);
            local_cnt += 1.0f;
        }
    }
    for (int off = 32; off > 0; off >>= 1) {
        local_sum += __shfl_down(local_sum, off, 64);
        local_cnt += __shfl_down(local_cnt, off, 64);
    }
    __shared__ float s_sum[4];
    __shared__ float s_cnt[4];
    int wid  = threadIdx.x >> 6;
    int lane = threadIdx.x & 63;
    if (lane == 0) { s_sum[wid] = local_sum; s_cnt[wid] = local_cnt; }
    __syncthreads();
    if (threadIdx.x == 0) {
        float bs = 0.0f, bc = 0.0f;
        int nw = blockDim.x >> 6;
        for (int w = 0; w < nw; ++w) { bs += s_sum[w]; bc += s_cnt[w]; }
        atomicAdd(&acc[0], bs);
        atomicAdd(&acc[1], bc);
    }
}

__global__ void cbl_finalize_kernel(const float* __restrict__ acc,
                                    float* __restrict__ out) {
    out[0] = acc[0] / fmaxf(acc[1], 1.0f);
}

extern "C" void kernel_launch(void* const* d_in, const int* in_sizes, int n_in,
                              void* d_out, int out_size, void* d_ws, size_t ws_size,
                              hipStream_t stream) {
    const int*   edge_index = (const int*)d_in[0];    // (2, E): [idx_i | idx_j]
    const float* logits     = (const float*)d_in[1];  // (E,)
    const int*   label      = (const int*)d_in[2];    // (N,)

    const int E = in_sizes[1];
    const int N = in_sizes[2];

    const int* idx_i = edge_index;
    const int* idx_j = edge_index + E;

    // ws layout: negsum f32[N] | possum f32[N] | acc f32[2] | lab16 u16[N]
    float*          negsum = (float*)d_ws;
    float*          possum = negsum + N;
    float*          acc    = possum + N;
    unsigned short* lab16  = (unsigned short*)(acc + 2);

    // zero the accumulators (negsum, possum, acc)
    hipMemsetAsync(d_ws, 0, (size_t)N * 8 + 8, stream);

    const int block = 256;
    cbl_pack_labels<<<(N + block - 1) / block, block, 0, stream>>>(label, lab16, N);

    if ((E & 3) == 0 && ((uintptr_t)idx_j % 16) == 0) {
        int nthreads = E / 4;
        int grid = (nthreads + block - 1) / block;
        cbl_edge_kernel_v4<<<grid, block, 0, stream>>>(idx_i, idx_j, logits,
                                                       lab16, negsum, possum, E);
    } else {
        int grid = (E + block - 1) / block;
        if (grid > 8192) grid = 8192;
        cbl_edge_kernel_scalar<<<grid, block, 0, stream>>>(idx_i, idx_j, logits,
                                                           lab16, negsum, possum, E);
    }

    int grid_n = (N + block - 1) / block;
    if (grid_n > 1024) grid_n = 1024;
    cbl_node_kernel<<<grid_n, block, 0, stream>>>(negsum, possum, acc, N);

    cbl_finalize_kernel<<<1, 1, 0, stream>>>(acc, (float*)d_out);
}

// Round 3
// 341.299 us; speedup vs baseline: 1.0911x; 1.0438x over previous
//
#include <hip/hip_runtime.h>

#define INV_T (1.0f / 0.07f)
#define EPS   1e-8f

// ---------------------------------------------------------------------------
// Label compression: int32 -> u16 (IGNORE -1 -> 0xFFFF). 200KB, L2-resident.
// ---------------------------------------------------------------------------
__global__ void cbl_pack_labels(const int* __restrict__ label,
                                unsigned short* __restrict__ lab16,
                                int N) {
    int i = blockIdx.x * blockDim.x + threadIdx.x;
    if (i < N) {
        int v = label[i];
        lab16[i] = (v == -1) ? 0xFFFFu : (unsigned short)v;
    }
}

// ---------------------------------------------------------------------------
// Edge pass. USE_XCD=1: each XCD accumulates into its PRIVATE copy of the
// [node]{neg,pos} array using workgroup-scope atomics (sc1=0 -> RMW executes
// at the XCD-local L2 instead of the cross-XCD fabric coherence point, which
// round 2 measured at only ~19G atomics/s). Correct because only blocks
// physically on XCD k (read via HW_REG_XCC_ID, not blockIdx heuristics) ever
// touch copy k, so all accesses to a given line go through one L2. The
// kernel-end device-scope release makes the dirty lines visible to the next
// kernel.  USE_XCD=0 fallback: single copy, device-scope atomics.
// ---------------------------------------------------------------------------
template <int USE_XCD>
__device__ __forceinline__ void cbl_process_edge(int i, unsigned short li,
                                                 unsigned short lj, float w,
                                                 float* __restrict__ buf) {
    if (li == 0xFFFFu || lj == 0xFFFFu) return;
    int slot = (i << 1) | (li == lj ? 1 : 0);   // even=neg, odd=pos
    if (USE_XCD) {
        __hip_atomic_fetch_add(buf + slot, w, __ATOMIC_RELAXED,
                               __HIP_MEMORY_SCOPE_WORKGROUP);
    } else {
        __hip_atomic_fetch_add(buf + slot, w, __ATOMIC_RELAXED,
                               __HIP_MEMORY_SCOPE_AGENT);
    }
}

template <int USE_XCD>
__global__ __launch_bounds__(256) void cbl_edge_v4(
    const int* __restrict__ idx_i,
    const int* __restrict__ idx_j,
    const float* __restrict__ logits,
    const unsigned short* __restrict__ lab16,
    float* __restrict__ bufs,
    int E, int stride2N) {
    int xcc = 0;
    if (USE_XCD) {
        asm volatile("s_getreg_b32 %0, hwreg(HW_REG_XCC_ID)" : "=s"(xcc));
        xcc &= 7;
    }
    float* buf = bufs + (size_t)xcc * (size_t)stride2N;

    int g = blockIdx.x * blockDim.x + threadIdx.x;
    int base = g * 4;
    if (base >= E) return;

    int4   ii = *reinterpret_cast<const int4*>(idx_i + base);
    int4   jj = *reinterpret_cast<const int4*>(idx_j + base);
    float4 lg = *reinterpret_cast<const float4*>(logits + base);

    unsigned short li0 = lab16[ii.x], li1 = lab16[ii.y];
    unsigned short li2 = lab16[ii.z], li3 = lab16[ii.w];
    unsigned short lj0 = lab16[jj.x], lj1 = lab16[jj.y];
    unsigned short lj2 = lab16[jj.z], lj3 = lab16[jj.w];

    float w0 = __expf(lg.x * INV_T);
    float w1 = __expf(lg.y * INV_T);
    float w2 = __expf(lg.z * INV_T);
    float w3 = __expf(lg.w * INV_T);

    cbl_process_edge<USE_XCD>(ii.x, li0, lj0, w0, buf);
    cbl_process_edge<USE_XCD>(ii.y, li1, lj1, w1, buf);
    cbl_process_edge<USE_XCD>(ii.z, li2, lj2, w2, buf);
    cbl_process_edge<USE_XCD>(ii.w, li3, lj3, w3, buf);
}

// scalar path (only if E % 4 != 0)
template <int USE_XCD>
__global__ __launch_bounds__(256) void cbl_edge_scalar(
    const int* __restrict__ idx_i,
    const int* __restrict__ idx_j,
    const float* __restrict__ logits,
    const unsigned short* __restrict__ lab16,
    float* __restrict__ bufs,
    int E, int stride2N) {
    int xcc = 0;
    if (USE_XCD) {
        asm volatile("s_getreg_b32 %0, hwreg(HW_REG_XCC_ID)" : "=s"(xcc));
        xcc &= 7;
    }
    float* buf = bufs + (size_t)xcc * (size_t)stride2N;
    int stride = gridDim.x * blockDim.x;
    for (int e = blockIdx.x * blockDim.x + threadIdx.x; e < E; e += stride) {
        unsigned short li = lab16[idx_i[e]];
        unsigned short lj = lab16[idx_j[e]];
        float w = __expf(logits[e] * INV_T);
        cbl_process_edge<USE_XCD>(idx_i[e], li, lj, w, buf);
    }
}

// ---------------------------------------------------------------------------
// Reduce pass: sum the K copies, compute per-node loss, block-reduce.
// boundary <=> neg > 0 (each w = exp(..) > 0); den = neg + pos > 0 automatic.
// ---------------------------------------------------------------------------
template <int K>
__global__ __launch_bounds__(256) void cbl_reduce(
    const float* __restrict__ bufs, int stride2N,
    float* __restrict__ acc, int N) {
    float lsum = 0.0f, lcnt = 0.0f;
    int stride = gridDim.x * blockDim.x;
    for (int i = blockIdx.x * blockDim.x + threadIdx.x; i < N; i += stride) {
        float neg = 0.0f, pos = 0.0f;
#pragma unroll
        for (int k = 0; k < K; ++k) {
            float2 v = *reinterpret_cast<const float2*>(
                bufs + (size_t)k * (size_t)stride2N + 2 * i);
            neg += v.x;
            pos += v.y;
        }
        if (neg > 0.0f) {
            lsum += logf(neg + pos + EPS) - logf(pos + EPS);
            lcnt += 1.0f;
        }
    }
    for (int off = 32; off > 0; off >>= 1) {
        lsum += __shfl_down(lsum, off, 64);
        lcnt += __shfl_down(lcnt, off, 64);
    }
    __shared__ float s_sum[4];
    __shared__ float s_cnt[4];
    int wid  = threadIdx.x >> 6;
    int lane = threadIdx.x & 63;
    if (lane == 0) { s_sum[wid] = lsum; s_cnt[wid] = lcnt; }
    __syncthreads();
    if (threadIdx.x == 0) {
        float bs = 0.0f, bc = 0.0f;
        int nw = blockDim.x >> 6;
        for (int w = 0; w < nw; ++w) { bs += s_sum[w]; bc += s_cnt[w]; }
        atomicAdd(&acc[0], bs);
        atomicAdd(&acc[1], bc);
    }
}

__global__ void cbl_finalize_kernel(const float* __restrict__ acc,
                                    float* __restrict__ out) {
    out[0] = acc[0] / fmaxf(acc[1], 1.0f);
}

extern "C" void kernel_launch(void* const* d_in, const int* in_sizes, int n_in,
                              void* d_out, int out_size, void* d_ws, size_t ws_size,
                              hipStream_t stream) {
    const int*   edge_index = (const int*)d_in[0];    // (2, E): [idx_i | idx_j]
    const float* logits     = (const float*)d_in[1];  // (E,)
    const int*   label      = (const int*)d_in[2];    // (N,)

    const int E = in_sizes[1];
    const int N = in_sizes[2];

    const int* idx_i = edge_index;
    const int* idx_j = edge_index + E;

    const int    stride2N  = 2 * N;
    const size_t copyBytes = (size_t)stride2N * sizeof(float);
    const size_t need8 = 8 * copyBytes + 2 * sizeof(float)
                       + (size_t)N * sizeof(unsigned short);
    const int K = (ws_size >= need8) ? 8 : 1;

    // ws layout: bufs f32[K][2N] | acc f32[2] | lab16 u16[N]
    float*          bufs  = (float*)d_ws;
    float*          acc   = bufs + (size_t)K * stride2N;
    unsigned short* lab16 = (unsigned short*)(acc + 2);

    hipMemsetAsync(d_ws, 0, (size_t)K * copyBytes + 2 * sizeof(float), stream);

    const int block = 256;
    cbl_pack_labels<<<(N + block - 1) / block, block, 0, stream>>>(label, lab16, N);

    if ((E & 3) == 0) {
        int grid = (E / 4 + block - 1) / block;
        if (K == 8)
            cbl_edge_v4<1><<<grid, block, 0, stream>>>(idx_i, idx_j, logits,
                                                       lab16, bufs, E, stride2N);
        else
            cbl_edge_v4<0><<<grid, block, 0, stream>>>(idx_i, idx_j, logits,
                                                       lab16, bufs, E, stride2N);
    } else {
        int grid = (E + block - 1) / block;
        if (grid > 8192) grid = 8192;
        if (K == 8)
            cbl_edge_scalar<1><<<grid, block, 0, stream>>>(idx_i, idx_j, logits,
                                                           lab16, bufs, E, stride2N);
        else
            cbl_edge_scalar<0><<<grid, block, 0, stream>>>(idx_i, idx_j, logits,
                                                           lab16, bufs, E, stride2N);
    }

    int grid_n = (N + block - 1) / block;
    if (grid_n > 1024) grid_n = 1024;
    if (K == 8)
        cbl_reduce<8><<<grid_n, block, 0, stream>>>(bufs, stride2N, acc, N);
    else
        cbl_reduce<1><<<grid_n, block, 0, stream>>>(bufs, stride2N, acc, N);

    cbl_finalize_kernel<<<1, 1, 0, stream>>>(acc, (float*)d_out);
}

// Round 5
// 258.523 us; speedup vs baseline: 1.4405x; 1.3202x over previous
//
#include <hip/hip_runtime.h>

#define INV_T  (1.0f / 0.07f)
#define EPS    1e-8f

#define RSH     11                 // nodes per bucket = 2048
#define RNODES  (1 << RSH)
#define GSPLIT  16                 // blocks per bucket in accumulate
#define SBLK    256                // scatter block size
#define EPT     16                 // edges per thread in scatter
#define EPB     (SBLK * EPT)       // 4096 edges per scatter block

// ---------------------------------------------------------------------------
// K0: label -> u8 (IGNORE -1 -> 0xFF). 100KB, L1/L2-resident for gathers.
// ---------------------------------------------------------------------------
__global__ void cbl_pack_lab8(const int* __restrict__ label,
                              unsigned char* __restrict__ lab8, int N) {
    int i = blockIdx.x * blockDim.x + threadIdx.x;
    if (i < N) {
        int v = label[i];
        lab8[i] = (v == -1) ? 0xFFu : (unsigned char)v;
    }
}

// ---------------------------------------------------------------------------
// K1: exact bucket histogram of idx_i (LDS-private, then <=B global int
// atomics per block).
// ---------------------------------------------------------------------------
__global__ __launch_bounds__(256) void cbl_hist(const int* __restrict__ idx_i,
                                                unsigned* __restrict__ hist,
                                                int E, int B) {
    __shared__ unsigned sh[256];
    for (int t = threadIdx.x; t < B; t += 256) sh[t] = 0;
    __syncthreads();
    int n4 = E >> 2;
    int stride = gridDim.x * blockDim.x;
    const int4* v4 = reinterpret_cast<const int4*>(idx_i);
    for (int k = blockIdx.x * blockDim.x + threadIdx.x; k < n4; k += stride) {
        int4 v = v4[k];
        atomicAdd(&sh[v.x >> RSH], 1u);
        atomicAdd(&sh[v.y >> RSH], 1u);
        atomicAdd(&sh[v.z >> RSH], 1u);
        atomicAdd(&sh[v.w >> RSH], 1u);
    }
    __syncthreads();
    for (int t = threadIdx.x; t < B; t += 256)
        if (sh[t]) atomicAdd(&hist[t], sh[t]);
}

// ---------------------------------------------------------------------------
// K2: exclusive scan of B bucket counts -> base, cursor.
// ---------------------------------------------------------------------------
__global__ void cbl_scan(const unsigned* __restrict__ hist,
                         unsigned* __restrict__ base,
                         unsigned* __restrict__ cursor, int B) {
    if (threadIdx.x == 0 && blockIdx.x == 0) {
        unsigned s = 0;
        for (int b = 0; b < B; ++b) {
            base[b] = s;
            cursor[b] = s;
            s += hist[b];
        }
    }
}

// ---------------------------------------------------------------------------
// K3: scatter edges into bucket regions. Per block: LDS count -> reserve
// chunk per bucket (<=B global int atomics) -> write 8B payloads
// {local|lj, w}. Validity resolved in K4.
// ---------------------------------------------------------------------------
__global__ __launch_bounds__(SBLK) void cbl_scatter(
    const int* __restrict__ idx_i,
    const int* __restrict__ idx_j,
    const float* __restrict__ logits,
    const unsigned char* __restrict__ lab8,
    unsigned* __restrict__ cursor,
    uint2* __restrict__ payload,
    int E, int B) {
    __shared__ unsigned s_cnt[256];
    __shared__ unsigned s_base[256];

    for (int t = threadIdx.x; t < 256; t += SBLK) s_cnt[t] = 0;
    __syncthreads();

    const int blockStart = blockIdx.x * EPB;
    int           iarr[EPT];
    float         warr[EPT];
    unsigned char ljarr[EPT];

#pragma unroll
    for (int q = 0; q < EPT / 4; ++q) {
        int base = blockStart + (q * SBLK + threadIdx.x) * 4;
        if (base < E) {   // E % 4 == 0 guaranteed by launcher -> base+4 <= E
            int4   ii = *reinterpret_cast<const int4*>(idx_i + base);
            int4   jj = *reinterpret_cast<const int4*>(idx_j + base);
            float4 lg = *reinterpret_cast<const float4*>(logits + base);
            iarr[q * 4 + 0] = ii.x; iarr[q * 4 + 1] = ii.y;
            iarr[q * 4 + 2] = ii.z; iarr[q * 4 + 3] = ii.w;
            ljarr[q * 4 + 0] = lab8[jj.x]; ljarr[q * 4 + 1] = lab8[jj.y];
            ljarr[q * 4 + 2] = lab8[jj.z]; ljarr[q * 4 + 3] = lab8[jj.w];
            warr[q * 4 + 0] = __expf(lg.x * INV_T);
            warr[q * 4 + 1] = __expf(lg.y * INV_T);
            warr[q * 4 + 2] = __expf(lg.z * INV_T);
            warr[q * 4 + 3] = __expf(lg.w * INV_T);
            atomicAdd(&s_cnt[(ii.x >> RSH) & 255], 1u);
            atomicAdd(&s_cnt[(ii.y >> RSH) & 255], 1u);
            atomicAdd(&s_cnt[(ii.z >> RSH) & 255], 1u);
            atomicAdd(&s_cnt[(ii.w >> RSH) & 255], 1u);
        } else {
            iarr[q * 4 + 0] = iarr[q * 4 + 1] = -1;
            iarr[q * 4 + 2] = iarr[q * 4 + 3] = -1;
            warr[q * 4 + 0] = warr[q * 4 + 1] = 0.0f;
            warr[q * 4 + 2] = warr[q * 4 + 3] = 0.0f;
            ljarr[q * 4 + 0] = ljarr[q * 4 + 1] = 0xFFu;
            ljarr[q * 4 + 2] = ljarr[q * 4 + 3] = 0xFFu;
        }
    }
    __syncthreads();

    // reserve global chunks; reuse s_cnt as intra-block cursor
    for (int t = threadIdx.x; t < B; t += SBLK) {
        unsigned c = s_cnt[t];
        s_base[t] = c ? atomicAdd(&cursor[t], c) : 0u;
        s_cnt[t] = 0;
    }
    __syncthreads();

#pragma unroll
    for (int k = 0; k < EPT; ++k) {
        int i = iarr[k];
        if (i < 0) continue;
        int b = (i >> RSH) & 255;
        unsigned slot = s_base[b] + atomicAdd(&s_cnt[b], 1u);
        unsigned meta = (unsigned)(i & (RNODES - 1)) | ((unsigned)ljarr[k] << RSH);
        payload[slot] = make_uint2(meta, __float_as_uint(warr[k]));
    }
}

// ---------------------------------------------------------------------------
// K4: accumulate. Block (b,g) sums its 1/GSPLIT slice of bucket b's payloads
// into an LDS [2048][2] accumulator (on-CU LDS fp atomics), writes 16KB
// partial to global.
// ---------------------------------------------------------------------------
__global__ __launch_bounds__(256) void cbl_accum(
    const uint2* __restrict__ payload,
    const unsigned* __restrict__ base,
    const unsigned* __restrict__ hist,
    const unsigned char* __restrict__ lab8,
    float* __restrict__ partials,
    int N, int B) {
    int b = blockIdx.x / GSPLIT;
    int g = blockIdx.x % GSPLIT;

    __shared__ float         acc[RNODES * 2];   // 16KB
    __shared__ unsigned char slab[RNODES];      // 2KB

    for (int t = threadIdx.x; t < RNODES * 2; t += 256) acc[t] = 0.0f;
    int nodeBase = b << RSH;
    for (int t = threadIdx.x; t < RNODES; t += 256) {
        int n = nodeBase + t;
        slab[t] = (n < N) ? lab8[n] : 0xFFu;
    }
    __syncthreads();

    unsigned start = base[b], cnt = hist[b];
    unsigned per = (cnt + GSPLIT - 1) / GSPLIT;
    unsigned s = (unsigned)g * per;
    unsigned e = s + per; if (e > cnt) e = cnt;

    for (unsigned k = s + threadIdx.x; k < e; k += 256) {
        uint2 p = payload[start + k];
        unsigned local = p.x & (RNODES - 1);
        unsigned lj    = (p.x >> RSH) & 0xFFu;
        unsigned li    = slab[local];
        if (li == 0xFFu || lj == 0xFFu) continue;
        int slot = (int)(local << 1) | (li == lj ? 1 : 0);  // even=neg, odd=pos
        atomicAdd(&acc[slot], __uint_as_float(p.y));
    }
    __syncthreads();

    float* dst = partials + (size_t)blockIdx.x * (RNODES * 2);
    for (int t = threadIdx.x; t < RNODES * 2; t += 256) dst[t] = acc[t];
}

// ---------------------------------------------------------------------------
// K5: per-node loss from GSPLIT partials; block-reduce into acc2.
// boundary <=> neg > 0; den = neg + pos > 0 automatic.
// ---------------------------------------------------------------------------
__global__ __launch_bounds__(256) void cbl_loss(
    const float* __restrict__ partials,
    float* __restrict__ acc2, int N) {
    float lsum = 0.0f, lcnt = 0.0f;
    int stride = gridDim.x * blockDim.x;
    for (int n = blockIdx.x * blockDim.x + threadIdx.x; n < N; n += stride) {
        int b = n >> RSH;
        int local = n & (RNODES - 1);
        float neg = 0.0f, pos = 0.0f;
        for (int g = 0; g < GSPLIT; ++g) {
            const float* p = partials
                + (size_t)(b * GSPLIT + g) * (RNODES * 2) + local * 2;
            neg += p[0];
            pos += p[1];
        }
        if (neg > 0.0f) {
            lsum += logf(neg + pos + EPS) - logf(pos + EPS);
            lcnt += 1.0f;
        }
    }
    for (int off = 32; off > 0; off >>= 1) {
        lsum += __shfl_down(lsum, off, 64);
        lcnt += __shfl_down(lcnt, off, 64);
    }
    __shared__ float s_sum[4];
    __shared__ float s_cnt2[4];
    int wid = threadIdx.x >> 6, lane = threadIdx.x & 63;
    if (lane == 0) { s_sum[wid] = lsum; s_cnt2[wid] = lcnt; }
    __syncthreads();
    if (threadIdx.x == 0) {
        float bs = 0.0f, bc = 0.0f;
        for (int w = 0; w < 4; ++w) { bs += s_sum[w]; bc += s_cnt2[w]; }
        atomicAdd(&acc2[0], bs);
        atomicAdd(&acc2[1], bc);
    }
}

__global__ void cbl_finalize(const float* __restrict__ acc2,
                             float* __restrict__ out) {
    out[0] = acc2[0] / fmaxf(acc2[1], 1.0f);
}

// ---------------------------------------------------------------------------
// Fallback (small ws / odd shapes): single-copy device-scope atomic path.
// ---------------------------------------------------------------------------
__global__ __launch_bounds__(256) void cbl_edge_fb(
    const int* __restrict__ idx_i, const int* __restrict__ idx_j,
    const float* __restrict__ logits, const unsigned char* __restrict__ lab8,
    float* __restrict__ buf, int E) {
    int stride = gridDim.x * blockDim.x;
    for (int e = blockIdx.x * blockDim.x + threadIdx.x; e < E; e += stride) {
        unsigned char li = lab8[idx_i[e]];
        unsigned char lj = lab8[idx_j[e]];
        if (li == 0xFFu || lj == 0xFFu) continue;
        float w = __expf(logits[e] * INV_T);
        int slot = (idx_i[e] << 1) | (li == lj ? 1 : 0);
        atomicAdd(&buf[slot], w);
    }
}

__global__ __launch_bounds__(256) void cbl_loss_fb(
    const float* __restrict__ buf, float* __restrict__ acc2, int N) {
    float lsum = 0.0f, lcnt = 0.0f;
    int stride = gridDim.x * blockDim.x;
    for (int n = blockIdx.x * blockDim.x + threadIdx.x; n < N; n += stride) {
        float neg = buf[2 * n], pos = buf[2 * n + 1];
        if (neg > 0.0f) {
            lsum += logf(neg + pos + EPS) - logf(pos + EPS);
            lcnt += 1.0f;
        }
    }
    for (int off = 32; off > 0; off >>= 1) {
        lsum += __shfl_down(lsum, off, 64);
        lcnt += __shfl_down(lcnt, off, 64);
    }
    __shared__ float s_sum[4];
    __shared__ float s_cnt2[4];
    int wid = threadIdx.x >> 6, lane = threadIdx.x & 63;
    if (lane == 0) { s_sum[wid] = lsum; s_cnt2[wid] = lcnt; }
    __syncthreads();
    if (threadIdx.x == 0) {
        float bs = 0.0f, bc = 0.0f;
        for (int w = 0; w < 4; ++w) { bs += s_sum[w]; bc += s_cnt2[w]; }
        atomicAdd(&acc2[0], bs);
        atomicAdd(&acc2[1], bc);
    }
}

extern "C" void kernel_launch(void* const* d_in, const int* in_sizes, int n_in,
                              void* d_out, int out_size, void* d_ws, size_t ws_size,
                              hipStream_t stream) {
    const int*   edge_index = (const int*)d_in[0];    // (2, E): [idx_i | idx_j]
    const float* logits     = (const float*)d_in[1];  // (E,)
    const int*   label      = (const int*)d_in[2];    // (N,)

    const int E = in_sizes[1];
    const int N = in_sizes[2];
    const int* idx_i = edge_index;
    const int* idx_j = edge_index + E;

    const int B = (N + RNODES - 1) >> RSH;
    const int block = 256;

    // ws layout: hist u32[B] | base u32[B] | cursor u32[B] | acc2 f32[2]
    //          | lab8 u8[N] (pad 8) | payload uint2[E] | partials f32[B*G*2R]
    char* p = (char*)d_ws;
    unsigned* hist   = (unsigned*)p;            p += (size_t)B * 4;
    unsigned* base   = (unsigned*)p;            p += (size_t)B * 4;
    unsigned* cursor = (unsigned*)p;            p += (size_t)B * 4;
    float*    acc2   = (float*)p;               p += 8;
    unsigned char* lab8 = (unsigned char*)p;    p += ((size_t)N + 7) & ~(size_t)7;
    uint2*    payload = (uint2*)p;              p += (size_t)E * 8;
    float*    partials = (float*)p;             p += (size_t)B * GSPLIT * RNODES * 2 * 4;
    size_t need = (size_t)(p - (char*)d_ws);

    const bool fast = (ws_size >= need) && ((E & 3) == 0) && (B >= 1) &&
                      (B <= 256) && (E >= EPB);

    if (fast) {
        hipMemsetAsync(d_ws, 0, (size_t)B * 12 + 8, stream);
        cbl_pack_lab8<<<(N + block - 1) / block, block, 0, stream>>>(label, lab8, N);

        int g1 = (E / 4 + block - 1) / block; if (g1 > 2048) g1 = 2048;
        cbl_hist<<<g1, block, 0, stream>>>(idx_i, hist, E, B);
        cbl_scan<<<1, 64, 0, stream>>>(hist, base, cursor, B);

        int g3 = (E + EPB - 1) / EPB;
        cbl_scatter<<<g3, SBLK, 0, stream>>>(idx_i, idx_j, logits, lab8,
                                             cursor, payload, E, B);

        cbl_accum<<<B * GSPLIT, block, 0, stream>>>(payload, base, hist, lab8,
                                                    partials, N, B);

        int g5 = (N + block - 1) / block; if (g5 > 1024) g5 = 1024;
        cbl_loss<<<g5, block, 0, stream>>>(partials, acc2, N);
        cbl_finalize<<<1, 1, 0, stream>>>(acc2, (float*)d_out);
    } else {
        // fallback: buf f32[2N] | acc2 f32[2] | lab8 u8[N]
        float* buf = (float*)d_ws;
        float* facc = buf + (size_t)2 * N;
        unsigned char* flab = (unsigned char*)(facc + 2);
        hipMemsetAsync(d_ws, 0, (size_t)N * 8 + 8, stream);
        cbl_pack_lab8<<<(N + block - 1) / block, block, 0, stream>>>(label, flab, N);
        int ge = (E + block - 1) / block; if (ge > 8192) ge = 8192;
        cbl_edge_fb<<<ge, block, 0, stream>>>(idx_i, idx_j, logits, flab, buf, E);
        int g5 = (N + block - 1) / block; if (g5 > 1024) g5 = 1024;
        cbl_loss_fb<<<g5, block, 0, stream>>>(buf, facc, N);
        cbl_finalize<<<1, 1, 0, stream>>>(facc, (float*)d_out);
    }
}

// Round 9
// 116.473 us; speedup vs baseline: 3.1974x; 2.2196x over previous
//
#include <hip/hip_runtime.h>

#define INV_T  (1.0f / 0.07f)
#define EPS    1e-8f

#define RSH     11                 // nodes per bucket = 2048
#define RNODES  (1 << RSH)
#define GSPLIT  16                 // accum blocks per bucket
#define SBLK    256                // scatter block size
#define EPT     8                  // edges per thread in scatter
#define EPB     (SBLK * EPT)       // 2048 edges per scatter block
#define MAXB    256

// ---------------------------------------------------------------------------
// K0: label -> u8 (IGNORE -1 -> 0xFF). 100KB, cache-resident for gathers.
// ---------------------------------------------------------------------------
__global__ void cbl_pack_lab8(const int* __restrict__ label,
                              unsigned char* __restrict__ lab8, int N) {
    int i = blockIdx.x * blockDim.x + threadIdx.x;
    if (i < N) {
        int v = label[i];
        lab8[i] = (v == -1) ? 0xFFu : (unsigned char)v;
    }
}

// ---------------------------------------------------------------------------
// K1: scatter with per-block deterministic layout. Block blk owns payload
// region [blk*EPB, blk*EPB+EPB). Within it, buckets are laid out by a
// block-local prefix; per-bucket (prefix<<16|count) goes to table[blk][b].
// Per-WAVE LDS counters (4 copies) cut atomic contention 4x vs round 5;
// per-(wave,bucket) sub-chunks are disjoint by construction, so no cross-
// wave coordination is needed. No global histogram / scan / cursor at all.
// ---------------------------------------------------------------------------
__global__ __launch_bounds__(SBLK) void cbl_scatter(
    const int* __restrict__ idx_i,
    const int* __restrict__ idx_j,
    const float* __restrict__ logits,
    const unsigned char* __restrict__ lab8,
    unsigned* __restrict__ table,     // [nBlk][B]
    uint2* __restrict__ payload,      // [E]
    int E, int B) {
    __shared__ unsigned s_cnt[4][MAXB];   // per-wave counts, then cursors
    __shared__ unsigned s_wb[4][MAXB];    // per-wave global write base
    __shared__ unsigned s_tot[MAXB];
    __shared__ unsigned s_pref[MAXB];

    const int wave = threadIdx.x >> 6;
    const int lane = threadIdx.x & 63;

    for (int t = threadIdx.x; t < B; t += SBLK) {
        s_cnt[0][t] = 0; s_cnt[1][t] = 0; s_cnt[2][t] = 0; s_cnt[3][t] = 0;
    }
    __syncthreads();

    const int blockStart = blockIdx.x * EPB;
    int           iarr[EPT];
    float         warr[EPT];
    unsigned char ljarr[EPT];

#pragma unroll
    for (int q = 0; q < EPT / 4; ++q) {
        int base = blockStart + (q * SBLK + threadIdx.x) * 4;
        if (base < E) {   // E % 4 == 0 -> base+4 <= E
            int4   ii = *reinterpret_cast<const int4*>(idx_i + base);
            int4   jj = *reinterpret_cast<const int4*>(idx_j + base);
            float4 lg = *reinterpret_cast<const float4*>(logits + base);
            iarr[q * 4 + 0] = ii.x; iarr[q * 4 + 1] = ii.y;
            iarr[q * 4 + 2] = ii.z; iarr[q * 4 + 3] = ii.w;
            ljarr[q * 4 + 0] = lab8[jj.x]; ljarr[q * 4 + 1] = lab8[jj.y];
            ljarr[q * 4 + 2] = lab8[jj.z]; ljarr[q * 4 + 3] = lab8[jj.w];
            warr[q * 4 + 0] = __expf(lg.x * INV_T);
            warr[q * 4 + 1] = __expf(lg.y * INV_T);
            warr[q * 4 + 2] = __expf(lg.z * INV_T);
            warr[q * 4 + 3] = __expf(lg.w * INV_T);
            atomicAdd(&s_cnt[wave][(ii.x >> RSH) & (MAXB - 1)], 1u);
            atomicAdd(&s_cnt[wave][(ii.y >> RSH) & (MAXB - 1)], 1u);
            atomicAdd(&s_cnt[wave][(ii.z >> RSH) & (MAXB - 1)], 1u);
            atomicAdd(&s_cnt[wave][(ii.w >> RSH) & (MAXB - 1)], 1u);
        } else {
            iarr[q * 4 + 0] = iarr[q * 4 + 1] = -1;
            iarr[q * 4 + 2] = iarr[q * 4 + 3] = -1;
            warr[q * 4 + 0] = warr[q * 4 + 1] = 0.0f;
            warr[q * 4 + 2] = warr[q * 4 + 3] = 0.0f;
            ljarr[q * 4 + 0] = ljarr[q * 4 + 1] = 0xFFu;
            ljarr[q * 4 + 2] = ljarr[q * 4 + 3] = 0xFFu;
        }
    }
    __syncthreads();

    // per-bucket block totals
    for (int t = threadIdx.x; t < B; t += SBLK)
        s_tot[t] = s_cnt[0][t] + s_cnt[1][t] + s_cnt[2][t] + s_cnt[3][t];
    __syncthreads();

    // exclusive prefix over buckets (wave-parallel if B<=64, else serial)
    if (B <= 64) {
        if (threadIdx.x < 64) {
            unsigned v = (lane < B) ? s_tot[lane] : 0u;
            unsigned incl = v;
            for (int off = 1; off < 64; off <<= 1) {
                unsigned n = __shfl_up(incl, off, 64);
                if (lane >= off) incl += n;
            }
            if (lane < B) s_pref[lane] = incl - v;
        }
    } else {
        if (threadIdx.x == 0) {
            unsigned r = 0;
            for (int b = 0; b < B; ++b) { s_pref[b] = r; r += s_tot[b]; }
        }
    }
    __syncthreads();

    // publish table row, derive per-wave bases, reset counters to cursors
    for (int t = threadIdx.x; t < B; t += SBLK) {
        unsigned pref = s_pref[t];
        table[(size_t)blockIdx.x * B + t] = (pref << 16) | s_tot[t];
        unsigned gb = (unsigned)blockStart + pref;
        s_wb[0][t] = gb;  gb += s_cnt[0][t];
        s_wb[1][t] = gb;  gb += s_cnt[1][t];
        s_wb[2][t] = gb;  gb += s_cnt[2][t];
        s_wb[3][t] = gb;
        s_cnt[0][t] = 0; s_cnt[1][t] = 0; s_cnt[2][t] = 0; s_cnt[3][t] = 0;
    }
    __syncthreads();

#pragma unroll
    for (int k = 0; k < EPT; ++k) {
        int i = iarr[k];
        if (i < 0) continue;
        int b = (i >> RSH) & (MAXB - 1);
        unsigned slot = s_wb[wave][b] + atomicAdd(&s_cnt[wave][b], 1u);
        unsigned meta = (unsigned)(i & (RNODES - 1)) | ((unsigned)ljarr[k] << RSH);
        payload[slot] = make_uint2(meta, __float_as_uint(warr[k]));
    }
}

// ---------------------------------------------------------------------------
// K2: accumulate. Block (b,g): each WAVE walks scatter-block chunks
// c = g*4+wave, step GSPLIT*4, reading table[c][b] (wave-uniform broadcast
// load) then the ~84-edge chunk, LDS fp-atomic into acc[2048][2].
// ---------------------------------------------------------------------------
__global__ __launch_bounds__(256) void cbl_accum(
    const uint2* __restrict__ payload,
    const unsigned* __restrict__ table,
    const unsigned char* __restrict__ lab8,
    float* __restrict__ partials,
    int N, int B, int nBlk) {
    int b = blockIdx.x / GSPLIT;
    int g = blockIdx.x % GSPLIT;

    __shared__ float         acc[RNODES * 2];   // 16KB
    __shared__ unsigned char slab[RNODES];      // 2KB

    for (int t = threadIdx.x; t < RNODES * 2; t += 256) acc[t] = 0.0f;
    int nodeBase = b << RSH;
    for (int t = threadIdx.x; t < RNODES; t += 256) {
        int n = nodeBase + t;
        slab[t] = (n < N) ? lab8[n] : 0xFFu;
    }
    __syncthreads();

    int wave = threadIdx.x >> 6, lane = threadIdx.x & 63;
    for (int c = g * 4 + wave; c < nBlk; c += GSPLIT * 4) {
        unsigned tbl  = table[(size_t)c * B + b];
        unsigned cnt  = tbl & 0xFFFFu;
        unsigned start = (unsigned)c * EPB + (tbl >> 16);
        for (unsigned k = lane; k < cnt; k += 64) {
            uint2 p = payload[start + k];
            unsigned local = p.x & (RNODES - 1);
            unsigned lj    = (p.x >> RSH) & 0xFFu;
            unsigned li    = slab[local];
            if (li == 0xFFu || lj == 0xFFu) continue;
            atomicAdd(&acc[(local << 1) | (li == lj ? 1 : 0)],
                      __uint_as_float(p.y));
        }
    }
    __syncthreads();

    float* dst = partials + (size_t)blockIdx.x * (RNODES * 2);
    for (int t = threadIdx.x; t < RNODES * 2; t += 256) dst[t] = acc[t];
}

// ---------------------------------------------------------------------------
// K3: per-node loss from GSPLIT partials; block-reduce into acc2.
// boundary <=> neg > 0; den = neg + pos > 0 automatic.
// ---------------------------------------------------------------------------
__global__ __launch_bounds__(256) void cbl_loss(
    const float* __restrict__ partials,
    float* __restrict__ acc2, int N) {
    float lsum = 0.0f, lcnt = 0.0f;
    int stride = gridDim.x * blockDim.x;
    for (int n = blockIdx.x * blockDim.x + threadIdx.x; n < N; n += stride) {
        int b = n >> RSH;
        int local = n & (RNODES - 1);
        float neg = 0.0f, pos = 0.0f;
#pragma unroll 4
        for (int g = 0; g < GSPLIT; ++g) {
            const float* p = partials
                + (size_t)(b * GSPLIT + g) * (RNODES * 2) + local * 2;
            float2 v = *reinterpret_cast<const float2*>(p);
            neg += v.x;
            pos += v.y;
        }
        if (neg > 0.0f) {
            lsum += logf(neg + pos + EPS) - logf(pos + EPS);
            lcnt += 1.0f;
        }
    }
    for (int off = 32; off > 0; off >>= 1) {
        lsum += __shfl_down(lsum, off, 64);
        lcnt += __shfl_down(lcnt, off, 64);
    }
    __shared__ float s_sum[4];
    __shared__ float s_cnt2[4];
    int wid = threadIdx.x >> 6, lane = threadIdx.x & 63;
    if (lane == 0) { s_sum[wid] = lsum; s_cnt2[wid] = lcnt; }
    __syncthreads();
    if (threadIdx.x == 0) {
        float bs = 0.0f, bc = 0.0f;
        for (int w = 0; w < 4; ++w) { bs += s_sum[w]; bc += s_cnt2[w]; }
        atomicAdd(&acc2[0], bs);
        atomicAdd(&acc2[1], bc);
    }
}

__global__ void cbl_finalize(const float* __restrict__ acc2,
                             float* __restrict__ out) {
    out[0] = acc2[0] / fmaxf(acc2[1], 1.0f);
}

// ---------------------------------------------------------------------------
// Fallback (small ws / odd shapes): single-copy device-scope atomic path.
// ---------------------------------------------------------------------------
__global__ __launch_bounds__(256) void cbl_edge_fb(
    const int* __restrict__ idx_i, const int* __restrict__ idx_j,
    const float* __restrict__ logits, const unsigned char* __restrict__ lab8,
    float* __restrict__ buf, int E) {
    int stride = gridDim.x * blockDim.x;
    for (int e = blockIdx.x * blockDim.x + threadIdx.x; e < E; e += stride) {
        unsigned char li = lab8[idx_i[e]];
        unsigned char lj = lab8[idx_j[e]];
        if (li == 0xFFu || lj == 0xFFu) continue;
        float w = __expf(logits[e] * INV_T);
        int slot = (idx_i[e] << 1) | (li == lj ? 1 : 0);
        atomicAdd(&buf[slot], w);
    }
}

__global__ __launch_bounds__(256) void cbl_loss_fb(
    const float* __restrict__ buf, float* __restrict__ acc2, int N) {
    float lsum = 0.0f, lcnt = 0.0f;
    int stride = gridDim.x * blockDim.x;
    for (int n = blockIdx.x * blockDim.x + threadIdx.x; n < N; n += stride) {
        float neg = buf[2 * n], pos = buf[2 * n + 1];
        if (neg > 0.0f) {
            lsum += logf(neg + pos + EPS) - logf(pos + EPS);
            lcnt += 1.0f;
        }
    }
    for (int off = 32; off > 0; off >>= 1) {
        lsum += __shfl_down(lsum, off, 64);
        lcnt += __shfl_down(lcnt, off, 64);
    }
    __shared__ float s_sum[4];
    __shared__ float s_cnt2[4];
    int wid = threadIdx.x >> 6, lane = threadIdx.x & 63;
    if (lane == 0) { s_sum[wid] = lsum; s_cnt2[wid] = lcnt; }
    __syncthreads();
    if (threadIdx.x == 0) {
        float bs = 0.0f, bc = 0.0f;
        for (int w = 0; w < 4; ++w) { bs += s_sum[w]; bc += s_cnt2[w]; }
        atomicAdd(&acc2[0], bs);
        atomicAdd(&acc2[1], bc);
    }
}

extern "C" void kernel_launch(void* const* d_in, const int* in_sizes, int n_in,
                              void* d_out, int out_size, void* d_ws, size_t ws_size,
                              hipStream_t stream) {
    const int*   edge_index = (const int*)d_in[0];    // (2, E): [idx_i | idx_j]
    const float* logits     = (const float*)d_in[1];  // (E,)
    const int*   label      = (const int*)d_in[2];    // (N,)

    const int E = in_sizes[1];
    const int N = in_sizes[2];
    const int* idx_i = edge_index;
    const int* idx_j = edge_index + E;

    const int B    = (N + RNODES - 1) >> RSH;
    const int nBlk = (E + EPB - 1) / EPB;
    const int block = 256;

    // ws layout: acc2 f32[2] | lab8 u8[N] (pad 8) | table u32[nBlk*B] (pad 8)
    //          | payload uint2[E] | partials f32[B*GSPLIT*RNODES*2]
    char* p = (char*)d_ws;
    float*    acc2   = (float*)p;               p += 8;
    unsigned char* lab8 = (unsigned char*)p;    p += ((size_t)N + 7) & ~(size_t)7;
    unsigned* table  = (unsigned*)p;            p += (((size_t)nBlk * B * 4) + 7) & ~(size_t)7;
    uint2*    payload = (uint2*)p;              p += (size_t)E * 8;
    float*    partials = (float*)p;             p += (size_t)B * GSPLIT * RNODES * 2 * 4;
    size_t need = (size_t)(p - (char*)d_ws);

    const bool fast = (ws_size >= need) && ((E & 3) == 0) && (E >= 4) &&
                      (B >= 1) && (B <= MAXB);

    if (fast) {
        hipMemsetAsync(acc2, 0, 8, stream);
        cbl_pack_lab8<<<(N + block - 1) / block, block, 0, stream>>>(label, lab8, N);

        cbl_scatter<<<nBlk, SBLK, 0, stream>>>(idx_i, idx_j, logits, lab8,
                                               table, payload, E, B);

        cbl_accum<<<B * GSPLIT, block, 0, stream>>>(payload, table, lab8,
                                                    partials, N, B, nBlk);

        int g5 = (N + block - 1) / block; if (g5 > 1024) g5 = 1024;
        cbl_loss<<<g5, block, 0, stream>>>(partials, acc2, N);
        cbl_finalize<<<1, 1, 0, stream>>>(acc2, (float*)d_out);
    } else {
        // fallback: buf f32[2N] | acc2 f32[2] | lab8 u8[N]
        float* buf = (float*)d_ws;
        float* facc = buf + (size_t)2 * N;
        unsigned char* flab = (unsigned char*)(facc + 2);
        hipMemsetAsync(d_ws, 0, (size_t)N * 8 + 8, stream);
        cbl_pack_lab8<<<(N + block - 1) / block, block, 0, stream>>>(label, flab, N);
        int ge = (E + block - 1) / block; if (ge > 8192) ge = 8192;
        cbl_edge_fb<<<ge, block, 0, stream>>>(idx_i, idx_j, logits, flab, buf, E);
        int g5 = (N + block - 1) / block; if (g5 > 1024) g5 = 1024;
        cbl_loss_fb<<<g5, block, 0, stream>>>(buf, facc, N);
        cbl_finalize<<<1, 1, 0, stream>>>(facc, (float*)d_out);
    }
}

// Round 11
// 107.062 us; speedup vs baseline: 3.4784x; 1.0879x over previous
//
#include <hip/hip_runtime.h>

#define INV_T  (1.0f / 0.07f)
#define EPS    1e-8f

#define RSH     11                 // nodes per bucket = 2048
#define RNODES  (1 << RSH)
#define GSPLIT  16                 // accum blocks per bucket
#define SBLK    256                // scatter block size
#define EPT     8                  // edges per thread in scatter
#define EPB     (SBLK * EPT)       // 2048 edges per scatter block
#define MAXB    256

// ---------------------------------------------------------------------------
// K0: label -> u8 (IGNORE -1 -> 0xFF). 100KB, cache-resident for gathers.
// ---------------------------------------------------------------------------
__global__ void cbl_pack_lab8(const int* __restrict__ label,
                              unsigned char* __restrict__ lab8, int N) {
    int i = blockIdx.x * blockDim.x + threadIdx.x;
    if (i < N) {
        int v = label[i];
        lab8[i] = (v == -1) ? 0xFFu : (unsigned char)v;
    }
}

// ---------------------------------------------------------------------------
// K1: scatter, per-block deterministic layout + LDS-STAGED COALESCED OUTPUT.
// Round 9 measured scatter latency-bound on scattered 8B stores (12.8M vmem
// transactions, VALUBusy 7%, HBM 16%). Phase B writes payloads to a 16KB
// LDS staging buffer at block-LOCAL slots (LDS absorbs the scatter), then
// the block streams the region out as contiguous uint4 stores
// (fully coalesced -> 4-8x fewer store transactions).
// ---------------------------------------------------------------------------
__global__ __launch_bounds__(SBLK) void cbl_scatter(
    const int* __restrict__ idx_i,
    const int* __restrict__ idx_j,
    const float* __restrict__ logits,
    const unsigned char* __restrict__ lab8,
    unsigned* __restrict__ table,     // [nBlk][B]
    uint2* __restrict__ payload,      // [E], 16B-aligned by launcher
    int E, int B) {
    __shared__ unsigned s_cnt[4][MAXB];   // per-wave counts, then cursors
    __shared__ unsigned s_wb[4][MAXB];    // per-wave LOCAL write base
    __shared__ unsigned s_tot[MAXB];
    __shared__ unsigned s_pref[MAXB];
    __shared__ uint2    s_stage[EPB];     // 16KB staging

    const int wave = threadIdx.x >> 6;
    const int lane = threadIdx.x & 63;

    for (int t = threadIdx.x; t < B; t += SBLK) {
        s_cnt[0][t] = 0; s_cnt[1][t] = 0; s_cnt[2][t] = 0; s_cnt[3][t] = 0;
    }
    __syncthreads();

    const int blockStart = blockIdx.x * EPB;
    int           iarr[EPT];
    float         warr[EPT];
    unsigned char ljarr[EPT];

#pragma unroll
    for (int q = 0; q < EPT / 4; ++q) {
        int base = blockStart + (q * SBLK + threadIdx.x) * 4;
        if (base < E) {   // E % 4 == 0 -> base+4 <= E
            int4   ii = *reinterpret_cast<const int4*>(idx_i + base);
            int4   jj = *reinterpret_cast<const int4*>(idx_j + base);
            float4 lg = *reinterpret_cast<const float4*>(logits + base);
            iarr[q * 4 + 0] = ii.x; iarr[q * 4 + 1] = ii.y;
            iarr[q * 4 + 2] = ii.z; iarr[q * 4 + 3] = ii.w;
            ljarr[q * 4 + 0] = lab8[jj.x]; ljarr[q * 4 + 1] = lab8[jj.y];
            ljarr[q * 4 + 2] = lab8[jj.z]; ljarr[q * 4 + 3] = lab8[jj.w];
            warr[q * 4 + 0] = __expf(lg.x * INV_T);
            warr[q * 4 + 1] = __expf(lg.y * INV_T);
            warr[q * 4 + 2] = __expf(lg.z * INV_T);
            warr[q * 4 + 3] = __expf(lg.w * INV_T);
            atomicAdd(&s_cnt[wave][(ii.x >> RSH) & (MAXB - 1)], 1u);
            atomicAdd(&s_cnt[wave][(ii.y >> RSH) & (MAXB - 1)], 1u);
            atomicAdd(&s_cnt[wave][(ii.z >> RSH) & (MAXB - 1)], 1u);
            atomicAdd(&s_cnt[wave][(ii.w >> RSH) & (MAXB - 1)], 1u);
        } else {
            iarr[q * 4 + 0] = iarr[q * 4 + 1] = -1;
            iarr[q * 4 + 2] = iarr[q * 4 + 3] = -1;
            warr[q * 4 + 0] = warr[q * 4 + 1] = 0.0f;
            warr[q * 4 + 2] = warr[q * 4 + 3] = 0.0f;
            ljarr[q * 4 + 0] = ljarr[q * 4 + 1] = 0xFFu;
            ljarr[q * 4 + 2] = ljarr[q * 4 + 3] = 0xFFu;
        }
    }
    __syncthreads();

    // per-bucket block totals
    for (int t = threadIdx.x; t < B; t += SBLK)
        s_tot[t] = s_cnt[0][t] + s_cnt[1][t] + s_cnt[2][t] + s_cnt[3][t];
    __syncthreads();

    // exclusive prefix over buckets (wave-parallel if B<=64, else serial)
    if (B <= 64) {
        if (threadIdx.x < 64) {
            unsigned v = (lane < B) ? s_tot[lane] : 0u;
            unsigned incl = v;
            for (int off = 1; off < 64; off <<= 1) {
                unsigned n = __shfl_up(incl, off, 64);
                if (lane >= off) incl += n;
            }
            if (lane < B) s_pref[lane] = incl - v;
        }
    } else {
        if (threadIdx.x == 0) {
            unsigned r = 0;
            for (int b = 0; b < B; ++b) { s_pref[b] = r; r += s_tot[b]; }
        }
    }
    __syncthreads();

    // publish table row, derive per-wave LOCAL bases, reset counters
    for (int t = threadIdx.x; t < B; t += SBLK) {
        unsigned pref = s_pref[t];
        table[(size_t)blockIdx.x * B + t] = (pref << 16) | s_tot[t];
        unsigned gb = pref;               // block-local slot base
        s_wb[0][t] = gb;  gb += s_cnt[0][t];
        s_wb[1][t] = gb;  gb += s_cnt[1][t];
        s_wb[2][t] = gb;  gb += s_cnt[2][t];
        s_wb[3][t] = gb;
        s_cnt[0][t] = 0; s_cnt[1][t] = 0; s_cnt[2][t] = 0; s_cnt[3][t] = 0;
    }
    __syncthreads();

    // phase B: scatter into LDS staging (local slots)
#pragma unroll
    for (int k = 0; k < EPT; ++k) {
        int i = iarr[k];
        if (i < 0) continue;
        int b = (i >> RSH) & (MAXB - 1);
        unsigned slot = s_wb[wave][b] + atomicAdd(&s_cnt[wave][b], 1u);
        unsigned meta = (unsigned)(i & (RNODES - 1)) | ((unsigned)ljarr[k] << RSH);
        s_stage[slot] = make_uint2(meta, __float_as_uint(warr[k]));
    }
    __syncthreads();

    // coalesced copy-out: lim uint2 = lim/2 uint4 (lim multiple of 4;
    // payload base and blockStart*8 are 16B-aligned)
    int lim = E - blockStart; if (lim > EPB) lim = EPB;
    int lim4 = lim >> 1;
    const uint4* src4 = reinterpret_cast<const uint4*>(s_stage);
    uint4* dst4 = reinterpret_cast<uint4*>(payload + blockStart);
    for (int t = threadIdx.x; t < lim4; t += SBLK) dst4[t] = src4[t];
}

// ---------------------------------------------------------------------------
// K2: accumulate. Block (b,g): each WAVE walks scatter-block chunks
// c = g*4+wave, step GSPLIT*4, reading table[c][b] (wave-uniform broadcast
// load) then the ~84-edge chunk, LDS fp-atomic into acc[2048][2].
// ---------------------------------------------------------------------------
__global__ __launch_bounds__(256) void cbl_accum(
    const uint2* __restrict__ payload,
    const unsigned* __restrict__ table,
    const unsigned char* __restrict__ lab8,
    float* __restrict__ partials,
    int N, int B, int nBlk) {
    int b = blockIdx.x / GSPLIT;
    int g = blockIdx.x % GSPLIT;

    __shared__ float         acc[RNODES * 2];   // 16KB
    __shared__ unsigned char slab[RNODES];      // 2KB

    for (int t = threadIdx.x; t < RNODES * 2; t += 256) acc[t] = 0.0f;
    int nodeBase = b << RSH;
    for (int t = threadIdx.x; t < RNODES; t += 256) {
        int n = nodeBase + t;
        slab[t] = (n < N) ? lab8[n] : 0xFFu;
    }
    __syncthreads();

    int wave = threadIdx.x >> 6, lane = threadIdx.x & 63;
    for (int c = g * 4 + wave; c < nBlk; c += GSPLIT * 4) {
        unsigned tbl  = table[(size_t)c * B + b];
        unsigned cnt  = tbl & 0xFFFFu;
        unsigned start = (unsigned)c * EPB + (tbl >> 16);
        for (unsigned k = lane; k < cnt; k += 64) {
            uint2 p = payload[start + k];
            unsigned local = p.x & (RNODES - 1);
            unsigned lj    = (p.x >> RSH) & 0xFFu;
            unsigned li    = slab[local];
            if (li == 0xFFu || lj == 0xFFu) continue;
            atomicAdd(&acc[(local << 1) | (li == lj ? 1 : 0)],
                      __uint_as_float(p.y));
        }
    }
    __syncthreads();

    float* dst = partials + (size_t)blockIdx.x * (RNODES * 2);
    for (int t = threadIdx.x; t < RNODES * 2; t += 256) dst[t] = acc[t];
}

// ---------------------------------------------------------------------------
// K3: per-node loss from GSPLIT partials; block-reduce into acc2.
// boundary <=> neg > 0; den = neg + pos > 0 automatic.
// ---------------------------------------------------------------------------
__global__ __launch_bounds__(256) void cbl_loss(
    const float* __restrict__ partials,
    float* __restrict__ acc2, int N) {
    float lsum = 0.0f, lcnt = 0.0f;
    int stride = gridDim.x * blockDim.x;
    for (int n = blockIdx.x * blockDim.x + threadIdx.x; n < N; n += stride) {
        int b = n >> RSH;
        int local = n & (RNODES - 1);
        float neg = 0.0f, pos = 0.0f;
#pragma unroll 4
        for (int g = 0; g < GSPLIT; ++g) {
            const float* p = partials
                + (size_t)(b * GSPLIT + g) * (RNODES * 2) + local * 2;
            float2 v = *reinterpret_cast<const float2*>(p);
            neg += v.x;
            pos += v.y;
        }
        if (neg > 0.0f) {
            lsum += logf(neg + pos + EPS) - logf(pos + EPS);
            lcnt += 1.0f;
        }
    }
    for (int off = 32; off > 0; off >>= 1) {
        lsum += __shfl_down(lsum, off, 64);
        lcnt += __shfl_down(lcnt, off, 64);
    }
    __shared__ float s_sum[4];
    __shared__ float s_cnt2[4];
    int wid = threadIdx.x >> 6, lane = threadIdx.x & 63;
    if (lane == 0) { s_sum[wid] = lsum; s_cnt2[wid] = lcnt; }
    __syncthreads();
    if (threadIdx.x == 0) {
        float bs = 0.0f, bc = 0.0f;
        for (int w = 0; w < 4; ++w) { bs += s_sum[w]; bc += s_cnt2[w]; }
        atomicAdd(&acc2[0], bs);
        atomicAdd(&acc2[1], bc);
    }
}

__global__ void cbl_finalize(const float* __restrict__ acc2,
                             float* __restrict__ out) {
    out[0] = acc2[0] / fmaxf(acc2[1], 1.0f);
}

// ---------------------------------------------------------------------------
// Fallback (small ws / odd shapes): single-copy device-scope atomic path.
// ---------------------------------------------------------------------------
__global__ __launch_bounds__(256) void cbl_edge_fb(
    const int* __restrict__ idx_i, const int* __restrict__ idx_j,
    const float* __restrict__ logits, const unsigned char* __restrict__ lab8,
    float* __restrict__ buf, int E) {
    int stride = gridDim.x * blockDim.x;
    for (int e = blockIdx.x * blockDim.x + threadIdx.x; e < E; e += stride) {
        unsigned char li = lab8[idx_i[e]];
        unsigned char lj = lab8[idx_j[e]];
        if (li == 0xFFu || lj == 0xFFu) continue;
        float w = __expf(logits[e] * INV_T);
        int slot = (idx_i[e] << 1) | (li == lj ? 1 : 0);
        atomicAdd(&buf[slot], w);
    }
}

__global__ __launch_bounds__(256) void cbl_loss_fb(
    const float* __restrict__ buf, float* __restrict__ acc2, int N) {
    float lsum = 0.0f, lcnt = 0.0f;
    int stride = gridDim.x * blockDim.x;
    for (int n = blockIdx.x * blockDim.x + threadIdx.x; n < N; n += stride) {
        float neg = buf[2 * n], pos = buf[2 * n + 1];
        if (neg > 0.0f) {
            lsum += logf(neg + pos + EPS) - logf(pos + EPS);
            lcnt += 1.0f;
        }
    }
    for (int off = 32; off > 0; off >>= 1) {
        lsum += __shfl_down(lsum, off, 64);
        lcnt += __shfl_down(lcnt, off, 64);
    }
    __shared__ float s_sum[4];
    __shared__ float s_cnt2[4];
    int wid = threadIdx.x >> 6, lane = threadIdx.x & 63;
    if (lane == 0) { s_sum[wid] = lsum; s_cnt2[wid] = lcnt; }
    __syncthreads();
    if (threadIdx.x == 0) {
        float bs = 0.0f, bc = 0.0f;
        for (int w = 0; w < 4; ++w) { bs += s_sum[w]; bc += s_cnt2[w]; }
        atomicAdd(&acc2[0], bs);
        atomicAdd(&acc2[1], bc);
    }
}

extern "C" void kernel_launch(void* const* d_in, const int* in_sizes, int n_in,
                              void* d_out, int out_size, void* d_ws, size_t ws_size,
                              hipStream_t stream) {
    const int*   edge_index = (const int*)d_in[0];    // (2, E): [idx_i | idx_j]
    const float* logits     = (const float*)d_in[1];  // (E,)
    const int*   label      = (const int*)d_in[2];    // (N,)

    const int E = in_sizes[1];
    const int N = in_sizes[2];
    const int* idx_i = edge_index;
    const int* idx_j = edge_index + E;

    const int B    = (N + RNODES - 1) >> RSH;
    const int nBlk = (E + EPB - 1) / EPB;
    const int block = 256;

    // ws layout (all sections padded to 16B so payload is uint4-aligned):
    // acc2 f32[2] | lab8 u8[N] | table u32[nBlk*B] | payload uint2[E]
    // | partials f32[B*GSPLIT*RNODES*2]
    char* p = (char*)d_ws;
    float*    acc2   = (float*)p;               p += 16;
    unsigned char* lab8 = (unsigned char*)p;    p += ((size_t)N + 15) & ~(size_t)15;
    unsigned* table  = (unsigned*)p;            p += (((size_t)nBlk * B * 4) + 15) & ~(size_t)15;
    uint2*    payload = (uint2*)p;              p += (size_t)E * 8;
    float*    partials = (float*)p;             p += (size_t)B * GSPLIT * RNODES * 2 * 4;
    size_t need = (size_t)(p - (char*)d_ws);

    const bool fast = (ws_size >= need) && ((E & 3) == 0) && (E >= 4) &&
                      (B >= 1) && (B <= MAXB) &&
                      (((uintptr_t)payload & 15) == 0);

    if (fast) {
        hipMemsetAsync(acc2, 0, 8, stream);
        cbl_pack_lab8<<<(N + block - 1) / block, block, 0, stream>>>(label, lab8, N);

        cbl_scatter<<<nBlk, SBLK, 0, stream>>>(idx_i, idx_j, logits, lab8,
                                               table, payload, E, B);

        cbl_accum<<<B * GSPLIT, block, 0, stream>>>(payload, table, lab8,
                                                    partials, N, B, nBlk);

        int g5 = (N + block - 1) / block; if (g5 > 1024) g5 = 1024;
        cbl_loss<<<g5, block, 0, stream>>>(partials, acc2, N);
        cbl_finalize<<<1, 1, 0, stream>>>(acc2, (float*)d_out);
    } else {
        // fallback: buf f32[2N] | acc2 f32[2] | lab8 u8[N]
        float* buf = (float*)d_ws;
        float* facc = buf + (size_t)2 * N;
        unsigned char* flab = (unsigned char*)(facc + 2);
        hipMemsetAsync(d_ws, 0, (size_t)N * 8 + 8, stream);
        cbl_pack_lab8<<<(N + block - 1) / block, block, 0, stream>>>(label, flab, N);
        int ge = (E + block - 1) / block; if (ge > 8192) ge = 8192;
        cbl_edge_fb<<<ge, block, 0, stream>>>(idx_i, idx_j, logits, flab, buf, E);
        int g5 = (N + block - 1) / block; if (g5 > 1024) g5 = 1024;
        cbl_loss_fb<<<g5, block, 0, stream>>>(buf, facc, N);
        cbl_finalize<<<1, 1, 0, stream>>>(facc, (float*)d_out);
    }
}